// Round 9
// baseline (133.402 us; speedup 1.0000x reference)
//
#include <hip/hip_runtime.h>
#include <cmath>

namespace {
constexpr int kB  = 256;
constexpr int kK1 = 4097;   // NCE_K + 1
constexpr int kN  = 100000; // N_DATA
constexpr float kInvT = 1.0f / 0.07f;
constexpr float kInvM = 1.0f / 4096.0f;
constexpr double kInvMd = 1.0 / 4096.0;
constexpr float kStdv = 0.15309311f;           // 1/sqrt(128/3)
constexpr float kQScale = 127.0f / kStdv;      // table quantize
constexpr float kQh    = 127.0f / 6.0f;        // query hi quant (clip +-6)
constexpr float kQhInv = 6.0f / 127.0f;
constexpr float kQl    = 127.0f * 127.0f / 6.0f;
constexpr float kDotT = (kStdv * 6.0f) / (127.0f * 127.0f * 127.0f * 0.07f);

// ---- v9 (LDS row-staged) layout ----
constexpr int kChunkRows = 128;                 // 32 KB LDS chunk
constexpr int kNChunks   = 782;                 // ceil(100000/128)
constexpr int kBinCap    = 32;                  // P(Poisson(5.24)>32) ~ 1e-15
constexpr size_t oTab   = 512;                              // int8 fused table
constexpr size_t oQtab  = oTab + (size_t)kN * 256;          // 25,600,512
constexpr size_t oBins9 = oQtab + (size_t)kB * 5 * 256;     // 25,928,192
constexpr size_t oCnt9  = oBins9 + (size_t)kNChunks * kB * kBinCap; // 32,334,336
constexpr size_t oPosA9 = oCnt9 + (size_t)kNChunks * kB;    // 32,534,528
constexpr size_t kNeed9 = oPosA9 + (size_t)kB * 5 * 4;      // 32,539,648

// v9 prep block roles
constexpr int kConvBlocks = (kN * 16) / 256;   // 6250
constexpr int kQQ0   = kConvBlocks;            // 40 blocks: query quant
constexpr int kScat0 = kQQ0 + 40;              // 256 blocks: chunk scatter
constexpr int kPos0  = kScat0 + kB;            // 8 blocks: positives
constexpr int kPrep9Blocks = kPos0 + 8;        // 6554

// ---- R8 fallback layout ----
constexpr int kSliceRows = 12500;
constexpr int kCap = 704;
constexpr size_t oSort = oTab + (size_t)kN * 256;
constexpr size_t oCnt2 = oSort + (size_t)kB * 8 * kCap * 2;
constexpr size_t oPosA = oCnt2 + 2048 * 4;
constexpr size_t kNeedFull = oPosA + (size_t)kB * 5 * 4;    // 28,497,408
constexpr int kConv8 = kConvBlocks;
constexpr int kScatBase8 = kConv8;
constexpr int kPosBase8  = kScatBase8 + kB;
constexpr int kPrep8Blocks = kPosBase8 + 8;
}

__device__ __forceinline__ int sdot4i(int a, int b, int c) {
#if __has_builtin(__builtin_amdgcn_sdot4)
    return __builtin_amdgcn_sdot4(a, b, c, false);
#else
    c += (int)(signed char)(a) * (int)(signed char)(b);
    c += (int)(signed char)(a >> 8) * (int)(signed char)(b >> 8);
    c += (int)(signed char)(a >> 16) * (int)(signed char)(b >> 16);
    c += (a >> 24) * (b >> 24);
    return c;
#endif
}

__device__ __forceinline__ int q8(float v, float s) {
    int q = __float2int_rn(v * s);
    return min(127, max(-127, q));
}

__device__ __forceinline__ int pack4(int a, int b, int c, int d) {
    return (a & 255) | ((b & 255) << 8) | ((c & 255) << 16) | ((d & 255) << 24);
}

// ============================ v9 prep =======================================
__global__ __launch_bounds__(256) void prep9_kernel(
    const float* __restrict__ feats_s, const float* __restrict__ f_t,
    const int* __restrict__ idx, const int* __restrict__ cidx,
    const float* __restrict__ mem_s, const float* __restrict__ mem_t,
    int4* __restrict__ tab, signed char* __restrict__ qtab,
    unsigned char* __restrict__ bins8, unsigned char* __restrict__ cnt8,
    float* __restrict__ posArr, double* __restrict__ ws)
{
    __shared__ int cnt[kNChunks];
    const int blk = blockIdx.x;
    const int tid = threadIdx.x;

    if (blk < kConvBlocks) {
        // ---- table conversion: one int4 (16 int8) per thread ----
        const int g = blk * 256 + tid;
        const int row  = g >> 4;
        const int r16  = g & 15;
        const int part = r16 >> 3;
        const int u    = r16 & 7;
        const float4* src = reinterpret_cast<const float4*>(part ? mem_t : mem_s)
                            + (size_t)row * 32 + u * 4;
        int w[4];
#pragma unroll
        for (int j = 0; j < 4; ++j) {
            const float4 v = src[j];
            w[j] = pack4(q8(v.x, kQScale), q8(v.y, kQScale),
                         q8(v.z, kQScale), q8(v.w, kQScale));
        }
        tab[g] = make_int4(w[0], w[1], w[2], w[3]);
    } else if (blk < kScat0) {
        // ---- query quantization: block j = q*8 + sl; thread = b ----
        const int j  = blk - kQQ0;
        const int q  = j >> 3;
        const int sl = j & 7;
        const int b  = tid;
        const float4* src = reinterpret_cast<const float4*>(
            (q == 0) ? (f_t + (size_t)b * 128)
                     : (feats_s + ((size_t)(q - 1) * kB + b) * 128)) + sl * 4;
        int hw[4], lw[4];
#pragma unroll
        for (int u = 0; u < 4; ++u) {
            const float4 v = src[u];
            const float x[4] = {v.x, v.y, v.z, v.w};
            int h[4], l[4];
#pragma unroll
            for (int e = 0; e < 4; ++e) {
                h[e] = q8(x[e], kQh);
                l[e] = q8(x[e] - (float)h[e] * kQhInv, kQl);
            }
            hw[u] = pack4(h[0], h[1], h[2], h[3]);
            lw[u] = pack4(l[0], l[1], l[2], l[3]);
        }
        int4* dh = reinterpret_cast<int4*>(qtab + (size_t)b * 1280 + q * 256 + sl * 16);
        int4* dl = reinterpret_cast<int4*>(qtab + (size_t)b * 1280 + q * 256 + 128 + sl * 16);
        *dh = make_int4(hw[0], hw[1], hw[2], hw[3]);
        *dl = make_int4(lw[0], lw[1], lw[2], lw[3]);
    } else if (blk < kPos0) {
        // ---- per-b chunk scatter (LDS counters, low contention) ----
        const int b = blk - kScat0;
        for (int i = tid; i < kNChunks; i += 256) cnt[i] = 0;
        if (blk == kScat0 && tid < 10) ws[tid] = 0.0;
        __syncthreads();
        for (int i = tid; i < 4096; i += 256) {
            const int r = cidx[(size_t)b * kK1 + 1 + i];
            const int c = r >> 7;
            const int p = atomicAdd(&cnt[c], 1);
            if (p < kBinCap)
                bins8[((size_t)c * kB + b) * kBinCap + p] = (unsigned char)(r & 127);
        }
        __syncthreads();
        for (int c = tid; c < kNChunks; c += 256)
            cnt8[(size_t)c * kB + b] = (unsigned char)min(cnt[c], kBinCap);
    } else {
        // ---- exact-f32 positives -> posArr ----
        const int b  = (blk - kPos0) * 32 + (tid >> 3);
        const int ol = tid & 7;
        const int row = idx[b];
        const float4* wsr = reinterpret_cast<const float4*>(mem_s + (size_t)row * 128);
        const float4* wtr = reinterpret_cast<const float4*>(mem_t + (size_t)row * 128);
        const float4* pft = reinterpret_cast<const float4*>(f_t + (size_t)b * 128);
        float d[5] = {0.f, 0.f, 0.f, 0.f, 0.f};
#pragma unroll
        for (int j = 0; j < 4; ++j) {
            const int e = ol + 8 * j;
            const float4 a  = wsr[e];
            const float4 c  = wtr[e];
            const float4 f0 = pft[e];
            d[0] += a.x * f0.x + a.y * f0.y + a.z * f0.z + a.w * f0.w;
#pragma unroll
            for (int q = 1; q < 5; ++q) {
                const float4 g = reinterpret_cast<const float4*>(
                    feats_s + ((size_t)(q - 1) * kB + b) * 128)[e];
                d[q] += c.x * g.x + c.y * g.y + c.z * g.z + c.w * g.w;
            }
        }
#pragma unroll
        for (int off = 1; off <= 4; off <<= 1)
#pragma unroll
            for (int q = 0; q < 5; ++q) d[q] += __shfl_xor(d[q], off);
        if (ol == 0) {
#pragma unroll
            for (int q = 0; q < 5; ++q) posArr[b * 5 + q] = d[q] * kInvT;
        }
    }
}

// ============================ v9 main =======================================
// grid (196, 4): block = (chunk-range of 4, b-group of 64). Octet o handles
// b = g*64+o and b+32 (2 query hi/lo sets in regs). Rows come from a 32KB
// LDS-staged chunk (sequential global stream -> not subject to the
// ~0.16 lines/cy/CU scattered-gather cap that held R1..R8 at >=43us).
__global__ __launch_bounds__(256) void mlcpc_v9_kernel(
    const int4* __restrict__ tab,
    const signed char* __restrict__ qtab,
    const unsigned char* __restrict__ bins8,
    const unsigned char* __restrict__ cnt8,
    double* __restrict__ ws)
{
    __shared__ int4 schunk[kChunkRows * 16];   // 32 KB, slot-swizzled
    __shared__ double sred[4][5];

    const int tid = threadIdx.x;
    const int ol  = tid & 7;
    const int o   = tid >> 3;            // octet 0..31
    const int g   = blockIdx.y;          // b-group 0..3
    const int c0  = blockIdx.x * 4;
    const int bA  = g * 64 + o;
    const int bB  = bA + 32;

    // query register sets (int4 each: 16 int8 = this lane's 16-elem slice)
    int4 qhA[5], qlA[5], qhB[5], qlB[5];
#pragma unroll
    for (int q = 0; q < 5; ++q) {
        const char* pa = (const char*)qtab + (size_t)bA * 1280 + q * 256 + ol * 16;
        const char* pb = (const char*)qtab + (size_t)bB * 1280 + q * 256 + ol * 16;
        qhA[q] = *reinterpret_cast<const int4*>(pa);
        qlA[q] = *reinterpret_cast<const int4*>(pa + 128);
        qhB[q] = *reinterpret_cast<const int4*>(pb);
        qlB[q] = *reinterpret_cast<const int4*>(pb + 128);
    }

    float acc = 0.f;   // per-lane role accumulator (role = ol, valid ol<5)

    for (int cc = 0; cc < 4; ++cc) {
        const int c = c0 + cc;
        if (c >= kNChunks) break;

        __syncthreads();   // protect previous chunk's readers
        // stage chunk: 2048 int4s, 8 per thread, swizzled slot = s ^ (row&7)
#pragma unroll
        for (int k = 0; k < 8; ++k) {
            const int i = tid + k * 256;
            const int r = i >> 4;
            const int s = i & 15;
            const int4 v = tab[(size_t)c * 2048 + i];
            schunk[r * 16 + ((s & 8) | ((s ^ r) & 7))] = v;
        }
        __syncthreads();

        // bin entries: 32B per (c,b); lane ol holds dword ol
        const int* bwA = reinterpret_cast<const int*>(
            bins8 + ((size_t)c * kB + bA) * kBinCap);
        const int* bwB = reinterpret_cast<const int*>(
            bins8 + ((size_t)c * kB + bB) * kBinCap);
        const int eA = bwA[ol];
        const int eB = bwB[ol];
        const int nA = cnt8[(size_t)c * kB + bA];
        const int nB = cnt8[(size_t)c * kB + bB];

#pragma unroll 1
        for (int j = 0; j < nA; ++j) {
            const int wsel = __shfl(eA, j >> 2, 8);
            const int r = (wsel >> ((j & 3) * 8)) & 127;
            const int slot = (ol ^ r) & 7;
            const int4 S = schunk[r * 16 + slot];
            const int4 T = schunk[r * 16 + 8 + slot];
            int X0, X1, X2, X3, X4;
            { int h = 0, l = 0;
              h = sdot4i(S.x, qhA[0].x, h); h = sdot4i(S.y, qhA[0].y, h);
              h = sdot4i(S.z, qhA[0].z, h); h = sdot4i(S.w, qhA[0].w, h);
              l = sdot4i(S.x, qlA[0].x, l); l = sdot4i(S.y, qlA[0].y, l);
              l = sdot4i(S.z, qlA[0].z, l); l = sdot4i(S.w, qlA[0].w, l);
              X0 = 127 * h + l; }
            { int h = 0, l = 0;
              h = sdot4i(T.x, qhA[1].x, h); h = sdot4i(T.y, qhA[1].y, h);
              h = sdot4i(T.z, qhA[1].z, h); h = sdot4i(T.w, qhA[1].w, h);
              l = sdot4i(T.x, qlA[1].x, l); l = sdot4i(T.y, qlA[1].y, l);
              l = sdot4i(T.z, qlA[1].z, l); l = sdot4i(T.w, qlA[1].w, l);
              X1 = 127 * h + l; }
            { int h = 0, l = 0;
              h = sdot4i(T.x, qhA[2].x, h); h = sdot4i(T.y, qhA[2].y, h);
              h = sdot4i(T.z, qhA[2].z, h); h = sdot4i(T.w, qhA[2].w, h);
              l = sdot4i(T.x, qlA[2].x, l); l = sdot4i(T.y, qlA[2].y, l);
              l = sdot4i(T.z, qlA[2].z, l); l = sdot4i(T.w, qlA[2].w, l);
              X2 = 127 * h + l; }
            { int h = 0, l = 0;
              h = sdot4i(T.x, qhA[3].x, h); h = sdot4i(T.y, qhA[3].y, h);
              h = sdot4i(T.z, qhA[3].z, h); h = sdot4i(T.w, qhA[3].w, h);
              l = sdot4i(T.x, qlA[3].x, l); l = sdot4i(T.y, qlA[3].y, l);
              l = sdot4i(T.z, qlA[3].z, l); l = sdot4i(T.w, qlA[3].w, l);
              X3 = 127 * h + l; }
            { int h = 0, l = 0;
              h = sdot4i(T.x, qhA[4].x, h); h = sdot4i(T.y, qhA[4].y, h);
              h = sdot4i(T.z, qhA[4].z, h); h = sdot4i(T.w, qhA[4].w, h);
              l = sdot4i(T.x, qlA[4].x, l); l = sdot4i(T.y, qlA[4].y, l);
              l = sdot4i(T.z, qlA[4].z, l); l = sdot4i(T.w, qlA[4].w, l);
              X4 = 127 * h + l; }
#pragma unroll
            for (int off = 1; off <= 4; off <<= 1) {
                X0 += __shfl_xor(X0, off); X1 += __shfl_xor(X1, off);
                X2 += __shfl_xor(X2, off); X3 += __shfl_xor(X3, off);
                X4 += __shfl_xor(X4, off);
            }
            if (ol < 5) {
                const int xs = (ol == 0) ? X0 : (ol == 1) ? X1
                             : (ol == 2) ? X2 : (ol == 3) ? X3 : X4;
                acc += expf((float)xs * kDotT);
            }
        }

#pragma unroll 1
        for (int j = 0; j < nB; ++j) {
            const int wsel = __shfl(eB, j >> 2, 8);
            const int r = (wsel >> ((j & 3) * 8)) & 127;
            const int slot = (ol ^ r) & 7;
            const int4 S = schunk[r * 16 + slot];
            const int4 T = schunk[r * 16 + 8 + slot];
            int X0, X1, X2, X3, X4;
            { int h = 0, l = 0;
              h = sdot4i(S.x, qhB[0].x, h); h = sdot4i(S.y, qhB[0].y, h);
              h = sdot4i(S.z, qhB[0].z, h); h = sdot4i(S.w, qhB[0].w, h);
              l = sdot4i(S.x, qlB[0].x, l); l = sdot4i(S.y, qlB[0].y, l);
              l = sdot4i(S.z, qlB[0].z, l); l = sdot4i(S.w, qlB[0].w, l);
              X0 = 127 * h + l; }
            { int h = 0, l = 0;
              h = sdot4i(T.x, qhB[1].x, h); h = sdot4i(T.y, qhB[1].y, h);
              h = sdot4i(T.z, qhB[1].z, h); h = sdot4i(T.w, qhB[1].w, h);
              l = sdot4i(T.x, qlB[1].x, l); l = sdot4i(T.y, qlB[1].y, l);
              l = sdot4i(T.z, qlB[1].z, l); l = sdot4i(T.w, qlB[1].w, l);
              X1 = 127 * h + l; }
            { int h = 0, l = 0;
              h = sdot4i(T.x, qhB[2].x, h); h = sdot4i(T.y, qhB[2].y, h);
              h = sdot4i(T.z, qhB[2].z, h); h = sdot4i(T.w, qhB[2].w, h);
              l = sdot4i(T.x, qlB[2].x, l); l = sdot4i(T.y, qlB[2].y, l);
              l = sdot4i(T.z, qlB[2].z, l); l = sdot4i(T.w, qlB[2].w, l);
              X2 = 127 * h + l; }
            { int h = 0, l = 0;
              h = sdot4i(T.x, qhB[3].x, h); h = sdot4i(T.y, qhB[3].y, h);
              h = sdot4i(T.z, qhB[3].z, h); h = sdot4i(T.w, qhB[3].w, h);
              l = sdot4i(T.x, qlB[3].x, l); l = sdot4i(T.y, qlB[3].y, l);
              l = sdot4i(T.z, qlB[3].z, l); l = sdot4i(T.w, qlB[3].w, l);
              X3 = 127 * h + l; }
            { int h = 0, l = 0;
              h = sdot4i(T.x, qhB[4].x, h); h = sdot4i(T.y, qhB[4].y, h);
              h = sdot4i(T.z, qhB[4].z, h); h = sdot4i(T.w, qhB[4].w, h);
              l = sdot4i(T.x, qlB[4].x, l); l = sdot4i(T.y, qlB[4].y, l);
              l = sdot4i(T.z, qlB[4].z, l); l = sdot4i(T.w, qlB[4].w, l);
              X4 = 127 * h + l; }
#pragma unroll
            for (int off = 1; off <= 4; off <<= 1) {
                X0 += __shfl_xor(X0, off); X1 += __shfl_xor(X1, off);
                X2 += __shfl_xor(X2, off); X3 += __shfl_xor(X3, off);
                X4 += __shfl_xor(X4, off);
            }
            if (ol < 5) {
                const int xs = (ol == 0) ? X0 : (ol == 1) ? X1
                             : (ol == 2) ? X2 : (ol == 3) ? X3 : X4;
                acc += expf((float)xs * kDotT);
            }
        }
    }

    // fold octets: lane L (<8) accumulates role L across the wave's 8 octets
#pragma unroll
    for (int off = 8; off <= 32; off <<= 1) acc += __shfl_down(acc, off);
    const int lane = tid & 63;
    const int wid  = tid >> 6;
    if (lane < 5) sred[wid][lane] = (double)acc;
    __syncthreads();
    if (tid < 5) {
        const double v = sred[0][tid] + sred[1][tid] + sred[2][tid] + sred[3][tid];
        atomicAdd(&ws[tid], v);
    }
}

__global__ void finalize2_kernel(const double* __restrict__ ws,
                                 const float* __restrict__ posArr,
                                 float* __restrict__ out) {
    const int t = threadIdx.x;   // 64 threads
    double e[5] = {0, 0, 0, 0, 0};
    double p[5] = {0, 0, 0, 0, 0};
    for (int b = t; b < kB; b += 64) {
#pragma unroll
        for (int q = 0; q < 5; ++q) {
            const double st = (double)posArr[b * 5 + q];
            p[q] += st;
            e[q] += exp(st);
        }
    }
#pragma unroll
    for (int off = 32; off >= 1; off >>= 1)
#pragma unroll
        for (int q = 0; q < 5; ++q) {
            e[q] += __shfl_down(e[q], off);
            p[q] += __shfl_down(p[q], off);
        }
    if (t == 0) {
        const double invB = 1.0 / 256.0;
        const double loss_t = 4.0 * (-(p[0] * invB) + log((ws[0] + kInvMd * e[0]) * invB));
        double loss_s = 0.0;
#pragma unroll
        for (int n = 1; n < 5; ++n)
            loss_s += -(p[n] * invB) + log((ws[n] + kInvMd * e[n]) * invB);
        out[0] = (float)(loss_s + loss_t);
    }
}

// ======================= R8 fallback (known-good, 74us) ======================
__global__ __launch_bounds__(256) void prep_kernel(
    const float* __restrict__ feats_s, const float* __restrict__ f_t,
    const int* __restrict__ idx, const int* __restrict__ cidx,
    const float* __restrict__ mem_s, const float* __restrict__ mem_t,
    int4* __restrict__ tab, unsigned short* __restrict__ sorted,
    int* __restrict__ cnt2, float* __restrict__ posArr,
    double* __restrict__ ws)
{
    __shared__ int posc[8];
    const int blk = blockIdx.x;
    const int tid = threadIdx.x;

    if (blk < kConv8) {
        const int g = blk * 256 + tid;
        const int row  = g >> 4;
        const int r16  = g & 15;
        const int part = r16 >> 3;
        const int u    = r16 & 7;
        const float4* src = reinterpret_cast<const float4*>(part ? mem_t : mem_s)
                            + (size_t)row * 32 + u * 4;
        int w[4];
#pragma unroll
        for (int j = 0; j < 4; ++j) {
            const float4 v = src[j];
            w[j] = pack4(q8(v.x, kQScale), q8(v.y, kQScale),
                         q8(v.z, kQScale), q8(v.w, kQScale));
        }
        tab[g] = make_int4(w[0], w[1], w[2], w[3]);
    } else if (blk < kPosBase8) {
        const int b = blk - kScatBase8;
        if (tid < 8) posc[tid] = 0;
        if (blk == kScatBase8 && tid >= 248) ws[tid - 248] = 0.0;
        __syncthreads();
        for (int i = tid; i < 4096; i += 256) {
            const int r = cidx[(size_t)b * kK1 + 1 + i];
            const int s = r / kSliceRows;
            const int p = atomicAdd(&posc[s], 1);
            if (p < kCap)
                sorted[(size_t)(b * 8 + s) * kCap + p] =
                    (unsigned short)(r - s * kSliceRows);
        }
        __syncthreads();
        if (tid < 8) cnt2[b * 8 + tid] = posc[tid];
    } else {
        const int b  = (blk - kPosBase8) * 32 + (tid >> 3);
        const int ol = tid & 7;
        const int row = idx[b];
        const float4* wsr = reinterpret_cast<const float4*>(mem_s + (size_t)row * 128);
        const float4* wtr = reinterpret_cast<const float4*>(mem_t + (size_t)row * 128);
        const float4* pft = reinterpret_cast<const float4*>(f_t + (size_t)b * 128);
        float d[5] = {0.f, 0.f, 0.f, 0.f, 0.f};
#pragma unroll
        for (int j = 0; j < 4; ++j) {
            const int e = ol + 8 * j;
            const float4 a  = wsr[e];
            const float4 c  = wtr[e];
            const float4 f0 = pft[e];
            d[0] += a.x * f0.x + a.y * f0.y + a.z * f0.z + a.w * f0.w;
#pragma unroll
            for (int q = 1; q < 5; ++q) {
                const float4 g = reinterpret_cast<const float4*>(
                    feats_s + ((size_t)(q - 1) * kB + b) * 128)[e];
                d[q] += c.x * g.x + c.y * g.y + c.z * g.z + c.w * g.w;
            }
        }
#pragma unroll
        for (int off = 1; off <= 4; off <<= 1)
#pragma unroll
            for (int q = 0; q < 5; ++q) d[q] += __shfl_xor(d[q], off);
        if (ol == 0) {
#pragma unroll
            for (int q = 0; q < 5; ++q) posArr[b * 5 + q] = d[q] * kInvT;
        }
    }
}

__global__ __launch_bounds__(256) void mlcpc_l2_kernel(
    const float* __restrict__ feats_s,
    const float* __restrict__ f_t,
    const int4*  __restrict__ tab,
    const unsigned short* __restrict__ sorted,
    const int*   __restrict__ cnt2,
    double*      __restrict__ ws)
{
    __shared__ alignas(16) int sqh[5][32];
    __shared__ alignas(16) int sql[5][32];
    __shared__ unsigned short slst[kCap];
    __shared__ double sred[4][5];

    const int g   = blockIdx.x;
    const int s   = g & 7;
    const int b   = g >> 3;
    const int tid = threadIdx.x;

    for (int i = tid; i < 160; i += 256) {
        const int q = i >> 5, w = i & 31;
        const float4 v = (q == 0)
            ? reinterpret_cast<const float4*>(f_t + (size_t)b * 128)[w]
            : reinterpret_cast<const float4*>(feats_s + ((size_t)(q - 1) * kB + b) * 128)[w];
        const float x[4] = {v.x, v.y, v.z, v.w};
        int h[4], l[4];
#pragma unroll
        for (int j = 0; j < 4; ++j) {
            h[j] = q8(x[j], kQh);
            l[j] = q8(x[j] - (float)h[j] * kQhInv, kQl);
        }
        sqh[q][w] = pack4(h[0], h[1], h[2], h[3]);
        sql[q][w] = pack4(l[0], l[1], l[2], l[3]);
    }
    const int len = min(cnt2[g], kCap);
    {
        const unsigned short* lst = sorted + (size_t)g * kCap;
        for (int i = tid; i < len; i += 256) slst[i] = lst[i];
    }
    __syncthreads();

    const int ol = tid & 7;
    const int oq = tid >> 3;

    int qh[5][4], ql[5][4];
#pragma unroll
    for (int q = 0; q < 5; ++q) {
        const int4 th = reinterpret_cast<const int4*>(sqh[q])[ol];
        const int4 tl = reinterpret_cast<const int4*>(sql[q])[ol];
        qh[q][0] = th.x; qh[q][1] = th.y; qh[q][2] = th.z; qh[q][3] = th.w;
        ql[q][0] = tl.x; ql[q][1] = tl.y; ql[q][2] = tl.z; ql[q][3] = tl.w;
    }

    const int rowbase = s * kSliceRows;
    float aqr = 0.f;

    int f = oq;
    bool v0 = f < len;
    bool v1 = (f + 32) < len;
    int4 S0, T0, S1, T1;
    if (v0) {
        const int4* rp = tab + (size_t)(rowbase + slst[f]) * 16;
        S0 = rp[ol]; T0 = rp[8 + ol];
    }
    if (v1) {
        const int4* rp = tab + (size_t)(rowbase + slst[f + 32]) * 16;
        S1 = rp[ol]; T1 = rp[8 + ol];
    }
    while (v0) {
        const bool v2 = (f + 64) < len;
        int4 S2, T2;
        if (v2) {
            const int4* rp = tab + (size_t)(rowbase + slst[f + 64]) * 16;
            S2 = rp[ol]; T2 = rp[8 + ol];
        }
        const int Sw[4] = {S0.x, S0.y, S0.z, S0.w};
        const int Tw[4] = {T0.x, T0.y, T0.z, T0.w};
        int X[5];
        {
            int h = 0, l = 0;
#pragma unroll
            for (int w = 0; w < 4; ++w) {
                h = sdot4i(Sw[w], qh[0][w], h);
                l = sdot4i(Sw[w], ql[0][w], l);
            }
            X[0] = 127 * h + l;
        }
#pragma unroll
        for (int q = 1; q < 5; ++q) {
            int h = 0, l = 0;
#pragma unroll
            for (int w = 0; w < 4; ++w) {
                h = sdot4i(Tw[w], qh[q][w], h);
                l = sdot4i(Tw[w], ql[q][w], l);
            }
            X[q] = 127 * h + l;
        }
#pragma unroll
        for (int off = 1; off <= 4; off <<= 1)
#pragma unroll
            for (int q = 0; q < 5; ++q) X[q] += __shfl_xor(X[q], off);
        if (ol < 5) aqr += expf((float)X[ol] * kDotT);

        S0 = S1; T0 = T1; S1 = S2; T1 = T2;
        v0 = v1; v1 = v2; f += 32;
    }

#pragma unroll
    for (int off = 8; off <= 32; off <<= 1) aqr += __shfl_down(aqr, off);
    const int lane = tid & 63;
    const int wid  = tid >> 6;
    if (lane < 5) sred[wid][lane] = (double)aqr;
    __syncthreads();
    if (tid < 5) {
        const double v = sred[0][tid] + sred[1][tid] + sred[2][tid] + sred[3][tid];
        atomicAdd(&ws[tid], v);
    }
}

// ------------------------- f32 fallback (round-1) ----------------------------
__global__ void init_ws_kernel(double* __restrict__ ws) {
    if (threadIdx.x < 10) ws[threadIdx.x] = 0.0;
}

__global__ __launch_bounds__(256) void mlcpc_main_kernel(
    const float* __restrict__ feats_s, const float* __restrict__ f_t,
    const int* __restrict__ idx, const int* __restrict__ cidx,
    const float* __restrict__ mem_s, const float* __restrict__ mem_t,
    double* __restrict__ ws)
{
    __shared__ float4 shf[5][32];
    __shared__ double sred[4][5];
    const int b = blockIdx.x, tid = threadIdx.x;
    for (int i = tid; i < 160; i += 256) {
        const int which = i >> 5, off = i & 31;
        const float* src = (which == 0) ? (f_t + (size_t)b * 128)
                                        : (feats_s + ((size_t)(which - 1) * kB + b) * 128);
        shf[which][off] = reinterpret_cast<const float4*>(src)[off];
    }
    __syncthreads();
    const int ql2 = tid & 3, gq = blockIdx.y * 64 + (tid >> 2);
    float aqt = 0.f, aq0 = 0.f, aq1 = 0.f, aq2 = 0.f, aq3 = 0.f;
    for (int k = gq; k < kK1; k += 512) {
        const int row = (k == 0) ? idx[b] : cidx[(size_t)b * kK1 + k];
        const float4* wsr = reinterpret_cast<const float4*>(mem_s + (size_t)row * 128);
        const float4* wtr = reinterpret_cast<const float4*>(mem_t + (size_t)row * 128);
        float dt = 0.f, d0 = 0.f, d1 = 0.f, d2 = 0.f, d3 = 0.f;
#pragma unroll
        for (int j = 0; j < 8; ++j) {
            const int e = ql2 + j * 4;
            const float4 a = wsr[e], c = wtr[e];
            const float4 ft = shf[0][e], g0 = shf[1][e], g1 = shf[2][e],
                         g2 = shf[3][e], g3 = shf[4][e];
            dt += a.x * ft.x + a.y * ft.y + a.z * ft.z + a.w * ft.w;
            d0 += c.x * g0.x + c.y * g0.y + c.z * g0.z + c.w * g0.w;
            d1 += c.x * g1.x + c.y * g1.y + c.z * g1.z + c.w * g1.w;
            d2 += c.x * g2.x + c.y * g2.y + c.z * g2.z + c.w * g2.w;
            d3 += c.x * g3.x + c.y * g3.y + c.z * g3.z + c.w * g3.w;
        }
#pragma unroll
        for (int off = 1; off <= 2; off <<= 1) {
            dt += __shfl_xor(dt, off); d0 += __shfl_xor(d0, off);
            d1 += __shfl_xor(d1, off); d2 += __shfl_xor(d2, off);
            d3 += __shfl_xor(d3, off);
        }
        if (ql2 == 0) {
            const float st = dt * kInvT, s0 = d0 * kInvT, s1 = d1 * kInvT,
                        s2 = d2 * kInvT, s3 = d3 * kInvT;
            const float w = (k == 0) ? kInvM : 1.0f;
            aqt += w * expf(st); aq0 += w * expf(s0); aq1 += w * expf(s1);
            aq2 += w * expf(s2); aq3 += w * expf(s3);
            if (k == 0) {
                atomicAdd(&ws[5], (double)st); atomicAdd(&ws[6], (double)s0);
                atomicAdd(&ws[7], (double)s1); atomicAdd(&ws[8], (double)s2);
                atomicAdd(&ws[9], (double)s3);
            }
        }
    }
#pragma unroll
    for (int off = 32; off >= 1; off >>= 1) {
        aqt += __shfl_down(aqt, off); aq0 += __shfl_down(aq0, off);
        aq1 += __shfl_down(aq1, off); aq2 += __shfl_down(aq2, off);
        aq3 += __shfl_down(aq3, off);
    }
    const int lane = tid & 63, wid = tid >> 6;
    if (lane == 0) {
        sred[wid][0] = (double)aqt; sred[wid][1] = (double)aq0;
        sred[wid][2] = (double)aq1; sred[wid][3] = (double)aq2;
        sred[wid][4] = (double)aq3;
    }
    __syncthreads();
    if (tid < 5) {
        const double sv = sred[0][tid] + sred[1][tid] + sred[2][tid] + sred[3][tid];
        atomicAdd(&ws[tid], sv);
    }
}

__global__ void finalize_kernel(const double* __restrict__ ws, float* __restrict__ out) {
    if (threadIdx.x == 0 && blockIdx.x == 0) {
        const double invB = 1.0 / 256.0;
        double loss_t = 4.0 * (-(ws[5] * invB) + log(ws[0] * invB));
        double loss_s = 0.0;
        for (int n = 0; n < 4; ++n)
            loss_s += -(ws[6 + n] * invB) + log(ws[1 + n] * invB);
        out[0] = (float)(loss_s + loss_t);
    }
}

// ----------------------------------- launch ----------------------------------
extern "C" void kernel_launch(void* const* d_in, const int* in_sizes, int n_in,
                              void* d_out, int out_size, void* d_ws, size_t ws_size,
                              hipStream_t stream) {
    const float* feats_s = (const float*)d_in[0];
    const float* f_t     = (const float*)d_in[1];
    const int*   idx     = (const int*)d_in[2];
    const int*   cidx    = (const int*)d_in[3];
    const float* mem_s   = (const float*)d_in[4];
    const float* mem_t   = (const float*)d_in[5];
    float* out = (float*)d_out;
    double* ws = (double*)d_ws;
    char* base = (char*)d_ws;

    if (ws_size >= kNeed9) {
        int4*           tab    = (int4*)(base + oTab);
        signed char*    qtab   = (signed char*)(base + oQtab);
        unsigned char*  bins8  = (unsigned char*)(base + oBins9);
        unsigned char*  cnt8   = (unsigned char*)(base + oCnt9);
        float*          posArr = (float*)(base + oPosA9);

        prep9_kernel<<<kPrep9Blocks, 256, 0, stream>>>(
            feats_s, f_t, idx, cidx, mem_s, mem_t,
            tab, qtab, bins8, cnt8, posArr, ws);
        mlcpc_v9_kernel<<<dim3(196, 4), 256, 0, stream>>>(
            (const int4*)tab, qtab, bins8, cnt8, ws);
        finalize2_kernel<<<1, 64, 0, stream>>>(ws, posArr, out);
    } else if (ws_size >= kNeedFull) {
        int4*           tab    = (int4*)(base + oTab);
        unsigned short* sorted = (unsigned short*)(base + oSort);
        int*            cnt2   = (int*)(base + oCnt2);
        float*          posArr = (float*)(base + oPosA);

        prep_kernel<<<kPrep8Blocks, 256, 0, stream>>>(
            feats_s, f_t, idx, cidx, mem_s, mem_t, tab, sorted, cnt2, posArr, ws);
        mlcpc_l2_kernel<<<kB * 8, 256, 0, stream>>>(
            feats_s, f_t, (const int4*)tab, sorted, cnt2, ws);
        finalize2_kernel<<<1, 64, 0, stream>>>(ws, posArr, out);
    } else {
        init_ws_kernel<<<1, 64, 0, stream>>>(ws);
        mlcpc_main_kernel<<<dim3(kB, 8), 256, 0, stream>>>(feats_s, f_t, idx, cidx,
                                                           mem_s, mem_t, ws);
        finalize_kernel<<<1, 64, 0, stream>>>(ws, out);
    }
}

// Round 10
// 109.385 us; speedup vs baseline: 1.2196x; 1.2196x over previous
//
#include <hip/hip_runtime.h>
#include <cmath>

namespace {
constexpr int kB  = 256;
constexpr int kK1 = 4097;   // NCE_K + 1
constexpr int kN  = 100000; // N_DATA
constexpr float kInvT = 1.0f / 0.07f;
constexpr float kInvM = 1.0f / 4096.0f;
constexpr double kInvMd = 1.0 / 4096.0;
constexpr float kStdv = 0.15309311f;           // 1/sqrt(128/3)
constexpr float kQScale = 127.0f / kStdv;      // table quantize
constexpr float kQh    = 127.0f / 6.0f;        // query hi quant (clip +-6)
constexpr float kQhInv = 6.0f / 127.0f;
constexpr float kQl    = 127.0f * 127.0f / 6.0f;
constexpr float kDotT = (kStdv * 6.0f) / (127.0f * 127.0f * 127.0f * 0.07f);

// ---- v10 (LDS row-staged, DPP-reduce) layout — same ws layout as v9 ----
constexpr int kChunkRows = 128;                 // 32 KB LDS chunk
constexpr int kNChunks   = 782;                 // ceil(100000/128)
constexpr int kBinCap    = 32;                  // P(Poisson(5.24)>32) ~ 1e-15
constexpr size_t oTab   = 512;
constexpr size_t oQtab  = oTab + (size_t)kN * 256;          // 25,600,512
constexpr size_t oBins9 = oQtab + (size_t)kB * 5 * 256;     // 25,928,192
constexpr size_t oCnt9  = oBins9 + (size_t)kNChunks * kB * kBinCap;
constexpr size_t oPosA9 = oCnt9 + (size_t)kNChunks * kB;
constexpr size_t kNeed9 = oPosA9 + (size_t)kB * 5 * 4;

// v10 prep block roles
constexpr int kConvB10 = (kN * 32) / 256;      // 12500 (one float4 pair / thread)
constexpr int kQQ10    = kConvB10;             // 40 blocks: query quant
constexpr int kScat10  = kQQ10 + 40;           // 256 blocks: chunk scatter
constexpr int kPos10   = kScat10 + kB;         // 8 blocks: positives
constexpr int kPrep10Blocks = kPos10 + 8;      // 12804

// ---- R8 fallback layout ----
constexpr int kSliceRows = 12500;
constexpr int kCap = 704;
constexpr size_t oSort = oTab + (size_t)kN * 256;
constexpr size_t oCnt2 = oSort + (size_t)kB * 8 * kCap * 2;
constexpr size_t oPosA = oCnt2 + 2048 * 4;
constexpr size_t kNeedFull = oPosA + (size_t)kB * 5 * 4;
constexpr int kConv8 = 6250;
constexpr int kScatBase8 = kConv8;
constexpr int kPosBase8  = kScatBase8 + kB;
constexpr int kPrep8Blocks = kPosBase8 + 8;
}

__device__ __forceinline__ int sdot4i(int a, int b, int c) {
#if __has_builtin(__builtin_amdgcn_sdot4)
    return __builtin_amdgcn_sdot4(a, b, c, false);
#else
    c += (int)(signed char)(a) * (int)(signed char)(b);
    c += (int)(signed char)(a >> 8) * (int)(signed char)(b >> 8);
    c += (int)(signed char)(a >> 16) * (int)(signed char)(b >> 16);
    c += (a >> 24) * (b >> 24);
    return c;
#endif
}

__device__ __forceinline__ int q8(float v, float s) {
    int q = __float2int_rn(v * s);
    return min(127, max(-127, q));
}

__device__ __forceinline__ int pack4(int a, int b, int c, int d) {
    return (a & 255) | ((b & 255) << 8) | ((c & 255) << 16) | ((d & 255) << 24);
}

// full 16-elem hi/lo dot contribution for this lane (X = 127*h + l)
__device__ __forceinline__ int dotX(const int4 m, const int4 h4, const int4 l4) {
    int h = 0, l = 0;
    h = sdot4i(m.x, h4.x, h); h = sdot4i(m.y, h4.y, h);
    h = sdot4i(m.z, h4.z, h); h = sdot4i(m.w, h4.w, h);
    l = sdot4i(m.x, l4.x, l); l = sdot4i(m.y, l4.y, l);
    l = sdot4i(m.z, l4.z, l); l = sdot4i(m.w, l4.w, l);
    return 127 * h + l;
}

// 8-lane (octet) sum via VALU-pipe DPP: xor1 (quad_perm 0xB1),
// xor2 (quad_perm 0x4E), xor7 (row_half_mirror 0x141). {1,2,7} generates
// {0..7} under xor -> every lane gets the full octet sum. No DS-pipe ops.
__device__ __forceinline__ int red8(int x) {
    x += __builtin_amdgcn_update_dpp(0, x, 0xB1, 0xF, 0xF, true);
    x += __builtin_amdgcn_update_dpp(0, x, 0x4E, 0xF, 0xF, true);
    x += __builtin_amdgcn_update_dpp(0, x, 0x141, 0xF, 0xF, true);
    return x;
}

// ============================ v10 prep ======================================
__global__ __launch_bounds__(256) void prep10_kernel(
    const float* __restrict__ feats_s, const float* __restrict__ f_t,
    const int* __restrict__ idx, const int* __restrict__ cidx,
    const float* __restrict__ mem_s, const float* __restrict__ mem_t,
    char* __restrict__ tabBytes, signed char* __restrict__ qtab,
    unsigned char* __restrict__ bins8, unsigned char* __restrict__ cnt8,
    float* __restrict__ posArr, double* __restrict__ ws)
{
    __shared__ int cnt[kNChunks];
    const int blk = blockIdx.x;
    const int tid = threadIdx.x;

    if (blk < kConvB10) {
        // ---- table conversion, fully coalesced: one float4 of each table ----
        const int g = blk * 256 + tid;        // 0 .. kN*32-1
        const float4 a = reinterpret_cast<const float4*>(mem_s)[g];
        const float4 c = reinterpret_cast<const float4*>(mem_t)[g];
        const int row = g >> 5, e4 = g & 31;
        char* dst = tabBytes + (size_t)row * 256 + e4 * 4;
        *reinterpret_cast<int*>(dst) =
            pack4(q8(a.x, kQScale), q8(a.y, kQScale), q8(a.z, kQScale), q8(a.w, kQScale));
        *reinterpret_cast<int*>(dst + 128) =
            pack4(q8(c.x, kQScale), q8(c.y, kQScale), q8(c.z, kQScale), q8(c.w, kQScale));
    } else if (blk < kScat10) {
        // ---- query quantization: block j = q*8 + sl; thread = b ----
        const int j  = blk - kQQ10;
        const int q  = j >> 3;
        const int sl = j & 7;
        const int b  = tid;
        const float4* src = reinterpret_cast<const float4*>(
            (q == 0) ? (f_t + (size_t)b * 128)
                     : (feats_s + ((size_t)(q - 1) * kB + b) * 128)) + sl * 4;
        int hw[4], lw[4];
#pragma unroll
        for (int u = 0; u < 4; ++u) {
            const float4 v = src[u];
            const float x[4] = {v.x, v.y, v.z, v.w};
            int h[4], l[4];
#pragma unroll
            for (int e = 0; e < 4; ++e) {
                h[e] = q8(x[e], kQh);
                l[e] = q8(x[e] - (float)h[e] * kQhInv, kQl);
            }
            hw[u] = pack4(h[0], h[1], h[2], h[3]);
            lw[u] = pack4(l[0], l[1], l[2], l[3]);
        }
        int4* dh = reinterpret_cast<int4*>(qtab + (size_t)b * 1280 + q * 256 + sl * 16);
        int4* dl = reinterpret_cast<int4*>(qtab + (size_t)b * 1280 + q * 256 + 128 + sl * 16);
        *dh = make_int4(hw[0], hw[1], hw[2], hw[3]);
        *dl = make_int4(lw[0], lw[1], lw[2], lw[3]);
    } else if (blk < kPos10) {
        // ---- per-b chunk scatter (LDS counters) ----
        const int b = blk - kScat10;
        for (int i = tid; i < kNChunks; i += 256) cnt[i] = 0;
        if (blk == kScat10 && tid < 10) ws[tid] = 0.0;
        __syncthreads();
        for (int i = tid; i < 4096; i += 256) {
            const int r = cidx[(size_t)b * kK1 + 1 + i];
            const int c = r >> 7;
            const int p = atomicAdd(&cnt[c], 1);
            if (p < kBinCap)
                bins8[((size_t)c * kB + b) * kBinCap + p] = (unsigned char)(r & 127);
        }
        __syncthreads();
        for (int c = tid; c < kNChunks; c += 256)
            cnt8[(size_t)c * kB + b] = (unsigned char)min(cnt[c], kBinCap);
    } else {
        // ---- exact-f32 positives -> posArr ----
        const int b  = (blk - kPos10) * 32 + (tid >> 3);
        const int ol = tid & 7;
        const int row = idx[b];
        const float4* wsr = reinterpret_cast<const float4*>(mem_s + (size_t)row * 128);
        const float4* wtr = reinterpret_cast<const float4*>(mem_t + (size_t)row * 128);
        const float4* pft = reinterpret_cast<const float4*>(f_t + (size_t)b * 128);
        float d[5] = {0.f, 0.f, 0.f, 0.f, 0.f};
#pragma unroll
        for (int j = 0; j < 4; ++j) {
            const int e = ol + 8 * j;
            const float4 a  = wsr[e];
            const float4 c  = wtr[e];
            const float4 f0 = pft[e];
            d[0] += a.x * f0.x + a.y * f0.y + a.z * f0.z + a.w * f0.w;
#pragma unroll
            for (int q = 1; q < 5; ++q) {
                const float4 g = reinterpret_cast<const float4*>(
                    feats_s + ((size_t)(q - 1) * kB + b) * 128)[e];
                d[q] += c.x * g.x + c.y * g.y + c.z * g.z + c.w * g.w;
            }
        }
#pragma unroll
        for (int off = 1; off <= 4; off <<= 1)
#pragma unroll
            for (int q = 0; q < 5; ++q) d[q] += __shfl_xor(d[q], off);
        if (ol == 0) {
#pragma unroll
            for (int q = 0; q < 5; ++q) posArr[b * 5 + q] = d[q] * kInvT;
        }
    }
}

// ============================ v10 main ======================================
// grid (782, 4) x 512 threads. Block = (chunk c, b-group of 64). Octet o owns
// b = g*64+o (queries in regs). Chunk staged once to LDS (sequential stream —
// escapes the ~0.16 lines/cy/CU scattered-gather cap). Octet reduction via
// DPP on the VALU pipe (v9's DS-pipe shuffle storm removed).
__global__ __launch_bounds__(512) void mlcpc_v10_kernel(
    const int4* __restrict__ tab,
    const signed char* __restrict__ qtab,
    const unsigned char* __restrict__ bins8,
    const unsigned char* __restrict__ cnt8,
    double* __restrict__ ws)
{
    __shared__ int4 schunk[kChunkRows * 16];      // 32 KB, slot-swizzled
    __shared__ alignas(16) int sbins[64 * 8];     // 2 KB bin entries
    __shared__ double sred[8][5];

    const int tid = threadIdx.x;
    const int ol  = tid & 7;
    const int o   = tid >> 3;            // octet 0..63
    const int c   = blockIdx.x;
    const int g   = blockIdx.y;
    const int b   = g * 64 + o;

    // this lane's 16-elem query slices, hi+lo, all 5 queries (40 VGPR)
    int4 qh[5], ql[5];
#pragma unroll
    for (int q = 0; q < 5; ++q) {
        const char* p = (const char*)qtab + (size_t)b * 1280 + q * 256 + ol * 16;
        qh[q] = *reinterpret_cast<const int4*>(p);
        ql[q] = *reinterpret_cast<const int4*>(p + 128);
    }

    // stage chunk (2048 int4, 4/thread), swizzled slot = (s&8)|((s^r)&7)
#pragma unroll
    for (int k = 0; k < 4; ++k) {
        const int i = tid + k * 512;
        const int r = i >> 4, s = i & 15;
        schunk[r * 16 + ((s & 8) | ((s ^ r) & 7))] = tab[(size_t)c * 2048 + i];
    }
    // stage bin entries for this (c, b-group): 2 KB contiguous
    if (tid < 128)
        reinterpret_cast<int4*>(sbins)[tid] =
            reinterpret_cast<const int4*>(bins8 + ((size_t)c * kB + g * 64) * kBinCap)[tid];
    __syncthreads();

    const int n  = cnt8[(size_t)c * kB + b];
    const int eA = sbins[o * 8 + ol];    // 4 entries/lane; octet holds all 32

    float acc = 0.f;   // per-lane role accumulator (role = ol, valid ol < 5)

    for (int jw = 0; jw < 8; ++jw) {
        if (jw * 4 >= n) break;          // octet-uniform
        const int wsel = __shfl(eA, jw, 8);   // broadcast lane jw of octet
        const int r0 = wsel & 127;
        const int r1 = (wsel >> 8) & 127;
        const int r2 = (wsel >> 16) & 127;
        const int r3 = (wsel >> 24) & 127;
        // issue all 8 row-loads up front (independent -> MLP)
        const int4 S0 = schunk[r0 * 16 + ((ol ^ r0) & 7)];
        const int4 T0 = schunk[r0 * 16 + 8 + ((ol ^ r0) & 7)];
        const int4 S1 = schunk[r1 * 16 + ((ol ^ r1) & 7)];
        const int4 T1 = schunk[r1 * 16 + 8 + ((ol ^ r1) & 7)];
        const int4 S2 = schunk[r2 * 16 + ((ol ^ r2) & 7)];
        const int4 T2 = schunk[r2 * 16 + 8 + ((ol ^ r2) & 7)];
        const int4 S3 = schunk[r3 * 16 + ((ol ^ r3) & 7)];
        const int4 T3 = schunk[r3 * 16 + 8 + ((ol ^ r3) & 7)];

#define V10_STEP(SS, TT, JJ)                                                  \
        {                                                                     \
            const int X0 = red8(dotX(SS, qh[0], ql[0]));                      \
            const int X1 = red8(dotX(TT, qh[1], ql[1]));                      \
            const int X2 = red8(dotX(TT, qh[2], ql[2]));                      \
            const int X3 = red8(dotX(TT, qh[3], ql[3]));                      \
            const int X4 = red8(dotX(TT, qh[4], ql[4]));                      \
            if ((jw * 4 + (JJ)) < n && ol < 5) {                              \
                const int xs = (ol == 0) ? X0 : (ol == 1) ? X1                \
                             : (ol == 2) ? X2 : (ol == 3) ? X3 : X4;          \
                acc += expf((float)xs * kDotT);                               \
            }                                                                 \
        }
        V10_STEP(S0, T0, 0)
        V10_STEP(S1, T1, 1)
        V10_STEP(S2, T2, 2)
        V10_STEP(S3, T3, 3)
#undef V10_STEP
    }

    // fold octets within wave, then waves via LDS
#pragma unroll
    for (int off = 8; off <= 32; off <<= 1) acc += __shfl_down(acc, off);
    const int lane = tid & 63;
    const int wid  = tid >> 6;
    if (lane < 5) sred[wid][lane] = (double)acc;
    __syncthreads();
    if (tid < 5) {
        double v = 0.0;
#pragma unroll
        for (int w = 0; w < 8; ++w) v += sred[w][tid];
        atomicAdd(&ws[tid], v);
    }
}

__global__ void finalize2_kernel(const double* __restrict__ ws,
                                 const float* __restrict__ posArr,
                                 float* __restrict__ out) {
    const int t = threadIdx.x;   // 64 threads
    double e[5] = {0, 0, 0, 0, 0};
    double p[5] = {0, 0, 0, 0, 0};
    for (int b = t; b < kB; b += 64) {
#pragma unroll
        for (int q = 0; q < 5; ++q) {
            const double st = (double)posArr[b * 5 + q];
            p[q] += st;
            e[q] += exp(st);
        }
    }
#pragma unroll
    for (int off = 32; off >= 1; off >>= 1)
#pragma unroll
        for (int q = 0; q < 5; ++q) {
            e[q] += __shfl_down(e[q], off);
            p[q] += __shfl_down(p[q], off);
        }
    if (t == 0) {
        const double invB = 1.0 / 256.0;
        const double loss_t = 4.0 * (-(p[0] * invB) + log((ws[0] + kInvMd * e[0]) * invB));
        double loss_s = 0.0;
#pragma unroll
        for (int n = 1; n < 5; ++n)
            loss_s += -(p[n] * invB) + log((ws[n] + kInvMd * e[n]) * invB);
        out[0] = (float)(loss_s + loss_t);
    }
}

// ======================= R8 fallback (known-good) ============================
__global__ __launch_bounds__(256) void prep_kernel(
    const float* __restrict__ feats_s, const float* __restrict__ f_t,
    const int* __restrict__ idx, const int* __restrict__ cidx,
    const float* __restrict__ mem_s, const float* __restrict__ mem_t,
    int4* __restrict__ tab, unsigned short* __restrict__ sorted,
    int* __restrict__ cnt2, float* __restrict__ posArr,
    double* __restrict__ ws)
{
    __shared__ int posc[8];
    const int blk = blockIdx.x;
    const int tid = threadIdx.x;

    if (blk < kConv8) {
        const int g = blk * 256 + tid;
        const int row  = g >> 4;
        const int r16  = g & 15;
        const int part = r16 >> 3;
        const int u    = r16 & 7;
        const float4* src = reinterpret_cast<const float4*>(part ? mem_t : mem_s)
                            + (size_t)row * 32 + u * 4;
        int w[4];
#pragma unroll
        for (int j = 0; j < 4; ++j) {
            const float4 v = src[j];
            w[j] = pack4(q8(v.x, kQScale), q8(v.y, kQScale),
                         q8(v.z, kQScale), q8(v.w, kQScale));
        }
        tab[g] = make_int4(w[0], w[1], w[2], w[3]);
    } else if (blk < kPosBase8) {
        const int b = blk - kScatBase8;
        if (tid < 8) posc[tid] = 0;
        if (blk == kScatBase8 && tid >= 248) ws[tid - 248] = 0.0;
        __syncthreads();
        for (int i = tid; i < 4096; i += 256) {
            const int r = cidx[(size_t)b * kK1 + 1 + i];
            const int s = r / kSliceRows;
            const int p = atomicAdd(&posc[s], 1);
            if (p < kCap)
                sorted[(size_t)(b * 8 + s) * kCap + p] =
                    (unsigned short)(r - s * kSliceRows);
        }
        __syncthreads();
        if (tid < 8) cnt2[b * 8 + tid] = posc[tid];
    } else {
        const int b  = (blk - kPosBase8) * 32 + (tid >> 3);
        const int ol = tid & 7;
        const int row = idx[b];
        const float4* wsr = reinterpret_cast<const float4*>(mem_s + (size_t)row * 128);
        const float4* wtr = reinterpret_cast<const float4*>(mem_t + (size_t)row * 128);
        const float4* pft = reinterpret_cast<const float4*>(f_t + (size_t)b * 128);
        float d[5] = {0.f, 0.f, 0.f, 0.f, 0.f};
#pragma unroll
        for (int j = 0; j < 4; ++j) {
            const int e = ol + 8 * j;
            const float4 a  = wsr[e];
            const float4 c  = wtr[e];
            const float4 f0 = pft[e];
            d[0] += a.x * f0.x + a.y * f0.y + a.z * f0.z + a.w * f0.w;
#pragma unroll
            for (int q = 1; q < 5; ++q) {
                const float4 g = reinterpret_cast<const float4*>(
                    feats_s + ((size_t)(q - 1) * kB + b) * 128)[e];
                d[q] += c.x * g.x + c.y * g.y + c.z * g.z + c.w * g.w;
            }
        }
#pragma unroll
        for (int off = 1; off <= 4; off <<= 1)
#pragma unroll
            for (int q = 0; q < 5; ++q) d[q] += __shfl_xor(d[q], off);
        if (ol == 0) {
#pragma unroll
            for (int q = 0; q < 5; ++q) posArr[b * 5 + q] = d[q] * kInvT;
        }
    }
}

__global__ __launch_bounds__(256) void mlcpc_l2_kernel(
    const float* __restrict__ feats_s,
    const float* __restrict__ f_t,
    const int4*  __restrict__ tab,
    const unsigned short* __restrict__ sorted,
    const int*   __restrict__ cnt2,
    double*      __restrict__ ws)
{
    __shared__ alignas(16) int sqh[5][32];
    __shared__ alignas(16) int sql[5][32];
    __shared__ unsigned short slst[kCap];
    __shared__ double sred[4][5];

    const int g   = blockIdx.x;
    const int s   = g & 7;
    const int b   = g >> 3;
    const int tid = threadIdx.x;

    for (int i = tid; i < 160; i += 256) {
        const int q = i >> 5, w = i & 31;
        const float4 v = (q == 0)
            ? reinterpret_cast<const float4*>(f_t + (size_t)b * 128)[w]
            : reinterpret_cast<const float4*>(feats_s + ((size_t)(q - 1) * kB + b) * 128)[w];
        const float x[4] = {v.x, v.y, v.z, v.w};
        int h[4], l[4];
#pragma unroll
        for (int j = 0; j < 4; ++j) {
            h[j] = q8(x[j], kQh);
            l[j] = q8(x[j] - (float)h[j] * kQhInv, kQl);
        }
        sqh[q][w] = pack4(h[0], h[1], h[2], h[3]);
        sql[q][w] = pack4(l[0], l[1], l[2], l[3]);
    }
    const int len = min(cnt2[g], kCap);
    {
        const unsigned short* lst = sorted + (size_t)g * kCap;
        for (int i = tid; i < len; i += 256) slst[i] = lst[i];
    }
    __syncthreads();

    const int ol = tid & 7;
    const int oq = tid >> 3;

    int qh[5][4], ql[5][4];
#pragma unroll
    for (int q = 0; q < 5; ++q) {
        const int4 th = reinterpret_cast<const int4*>(sqh[q])[ol];
        const int4 tl = reinterpret_cast<const int4*>(sql[q])[ol];
        qh[q][0] = th.x; qh[q][1] = th.y; qh[q][2] = th.z; qh[q][3] = th.w;
        ql[q][0] = tl.x; ql[q][1] = tl.y; ql[q][2] = tl.z; ql[q][3] = tl.w;
    }

    const int rowbase = s * kSliceRows;
    float aqr = 0.f;

    int f = oq;
    bool v0 = f < len;
    bool v1 = (f + 32) < len;
    int4 S0, T0, S1, T1;
    if (v0) {
        const int4* rp = tab + (size_t)(rowbase + slst[f]) * 16;
        S0 = rp[ol]; T0 = rp[8 + ol];
    }
    if (v1) {
        const int4* rp = tab + (size_t)(rowbase + slst[f + 32]) * 16;
        S1 = rp[ol]; T1 = rp[8 + ol];
    }
    while (v0) {
        const bool v2 = (f + 64) < len;
        int4 S2, T2;
        if (v2) {
            const int4* rp = tab + (size_t)(rowbase + slst[f + 64]) * 16;
            S2 = rp[ol]; T2 = rp[8 + ol];
        }
        const int Sw[4] = {S0.x, S0.y, S0.z, S0.w};
        const int Tw[4] = {T0.x, T0.y, T0.z, T0.w};
        int X[5];
        {
            int h = 0, l = 0;
#pragma unroll
            for (int w = 0; w < 4; ++w) {
                h = sdot4i(Sw[w], qh[0][w], h);
                l = sdot4i(Sw[w], ql[0][w], l);
            }
            X[0] = 127 * h + l;
        }
#pragma unroll
        for (int q = 1; q < 5; ++q) {
            int h = 0, l = 0;
#pragma unroll
            for (int w = 0; w < 4; ++w) {
                h = sdot4i(Tw[w], qh[q][w], h);
                l = sdot4i(Tw[w], ql[q][w], l);
            }
            X[q] = 127 * h + l;
        }
#pragma unroll
        for (int off = 1; off <= 4; off <<= 1)
#pragma unroll
            for (int q = 0; q < 5; ++q) X[q] += __shfl_xor(X[q], off);
        if (ol < 5) aqr += expf((float)X[ol] * kDotT);

        S0 = S1; T0 = T1; S1 = S2; T1 = T2;
        v0 = v1; v1 = v2; f += 32;
    }

#pragma unroll
    for (int off = 8; off <= 32; off <<= 1) aqr += __shfl_down(aqr, off);
    const int lane = tid & 63;
    const int wid  = tid >> 6;
    if (lane < 5) sred[wid][lane] = (double)aqr;
    __syncthreads();
    if (tid < 5) {
        const double v = sred[0][tid] + sred[1][tid] + sred[2][tid] + sred[3][tid];
        atomicAdd(&ws[tid], v);
    }
}

// ------------------------- f32 fallback (round-1) ----------------------------
__global__ void init_ws_kernel(double* __restrict__ ws) {
    if (threadIdx.x < 10) ws[threadIdx.x] = 0.0;
}

__global__ __launch_bounds__(256) void mlcpc_main_kernel(
    const float* __restrict__ feats_s, const float* __restrict__ f_t,
    const int* __restrict__ idx, const int* __restrict__ cidx,
    const float* __restrict__ mem_s, const float* __restrict__ mem_t,
    double* __restrict__ ws)
{
    __shared__ float4 shf[5][32];
    __shared__ double sred[4][5];
    const int b = blockIdx.x, tid = threadIdx.x;
    for (int i = tid; i < 160; i += 256) {
        const int which = i >> 5, off = i & 31;
        const float* src = (which == 0) ? (f_t + (size_t)b * 128)
                                        : (feats_s + ((size_t)(which - 1) * kB + b) * 128);
        shf[which][off] = reinterpret_cast<const float4*>(src)[off];
    }
    __syncthreads();
    const int ql2 = tid & 3, gq = blockIdx.y * 64 + (tid >> 2);
    float aqt = 0.f, aq0 = 0.f, aq1 = 0.f, aq2 = 0.f, aq3 = 0.f;
    for (int k = gq; k < kK1; k += 512) {
        const int row = (k == 0) ? idx[b] : cidx[(size_t)b * kK1 + k];
        const float4* wsr = reinterpret_cast<const float4*>(mem_s + (size_t)row * 128);
        const float4* wtr = reinterpret_cast<const float4*>(mem_t + (size_t)row * 128);
        float dt = 0.f, d0 = 0.f, d1 = 0.f, d2 = 0.f, d3 = 0.f;
#pragma unroll
        for (int j = 0; j < 8; ++j) {
            const int e = ql2 + j * 4;
            const float4 a = wsr[e], c = wtr[e];
            const float4 ft = shf[0][e], g0 = shf[1][e], g1 = shf[2][e],
                         g2 = shf[3][e], g3 = shf[4][e];
            dt += a.x * ft.x + a.y * ft.y + a.z * ft.z + a.w * ft.w;
            d0 += c.x * g0.x + c.y * g0.y + c.z * g0.z + c.w * g0.w;
            d1 += c.x * g1.x + c.y * g1.y + c.z * g1.z + c.w * g1.w;
            d2 += c.x * g2.x + c.y * g2.y + c.z * g2.z + c.w * g2.w;
            d3 += c.x * g3.x + c.y * g3.y + c.z * g3.z + c.w * g3.w;
        }
#pragma unroll
        for (int off = 1; off <= 2; off <<= 1) {
            dt += __shfl_xor(dt, off); d0 += __shfl_xor(d0, off);
            d1 += __shfl_xor(d1, off); d2 += __shfl_xor(d2, off);
            d3 += __shfl_xor(d3, off);
        }
        if (ql2 == 0) {
            const float st = dt * kInvT, s0 = d0 * kInvT, s1 = d1 * kInvT,
                        s2 = d2 * kInvT, s3 = d3 * kInvT;
            const float w = (k == 0) ? kInvM : 1.0f;
            aqt += w * expf(st); aq0 += w * expf(s0); aq1 += w * expf(s1);
            aq2 += w * expf(s2); aq3 += w * expf(s3);
            if (k == 0) {
                atomicAdd(&ws[5], (double)st); atomicAdd(&ws[6], (double)s0);
                atomicAdd(&ws[7], (double)s1); atomicAdd(&ws[8], (double)s2);
                atomicAdd(&ws[9], (double)s3);
            }
        }
    }
#pragma unroll
    for (int off = 32; off >= 1; off >>= 1) {
        aqt += __shfl_down(aqt, off); aq0 += __shfl_down(aq0, off);
        aq1 += __shfl_down(aq1, off); aq2 += __shfl_down(aq2, off);
        aq3 += __shfl_down(aq3, off);
    }
    const int lane = tid & 63, wid = tid >> 6;
    if (lane == 0) {
        sred[wid][0] = (double)aqt; sred[wid][1] = (double)aq0;
        sred[wid][2] = (double)aq1; sred[wid][3] = (double)aq2;
        sred[wid][4] = (double)aq3;
    }
    __syncthreads();
    if (tid < 5) {
        const double sv = sred[0][tid] + sred[1][tid] + sred[2][tid] + sred[3][tid];
        atomicAdd(&ws[tid], sv);
    }
}

__global__ void finalize_kernel(const double* __restrict__ ws, float* __restrict__ out) {
    if (threadIdx.x == 0 && blockIdx.x == 0) {
        const double invB = 1.0 / 256.0;
        double loss_t = 4.0 * (-(ws[5] * invB) + log(ws[0] * invB));
        double loss_s = 0.0;
        for (int n = 0; n < 4; ++n)
            loss_s += -(ws[6 + n] * invB) + log(ws[1 + n] * invB);
        out[0] = (float)(loss_s + loss_t);
    }
}

// ----------------------------------- launch ----------------------------------
extern "C" void kernel_launch(void* const* d_in, const int* in_sizes, int n_in,
                              void* d_out, int out_size, void* d_ws, size_t ws_size,
                              hipStream_t stream) {
    const float* feats_s = (const float*)d_in[0];
    const float* f_t     = (const float*)d_in[1];
    const int*   idx     = (const int*)d_in[2];
    const int*   cidx    = (const int*)d_in[3];
    const float* mem_s   = (const float*)d_in[4];
    const float* mem_t   = (const float*)d_in[5];
    float* out = (float*)d_out;
    double* ws = (double*)d_ws;
    char* base = (char*)d_ws;

    if (ws_size >= kNeed9) {
        char*           tabB   = base + oTab;
        signed char*    qtab   = (signed char*)(base + oQtab);
        unsigned char*  bins8  = (unsigned char*)(base + oBins9);
        unsigned char*  cnt8   = (unsigned char*)(base + oCnt9);
        float*          posArr = (float*)(base + oPosA9);

        prep10_kernel<<<kPrep10Blocks, 256, 0, stream>>>(
            feats_s, f_t, idx, cidx, mem_s, mem_t,
            tabB, qtab, bins8, cnt8, posArr, ws);
        mlcpc_v10_kernel<<<dim3(kNChunks, 4), 512, 0, stream>>>(
            (const int4*)tabB, qtab, bins8, cnt8, ws);
        finalize2_kernel<<<1, 64, 0, stream>>>(ws, posArr, out);
    } else if (ws_size >= kNeedFull) {
        int4*           tab    = (int4*)(base + oTab);
        unsigned short* sorted = (unsigned short*)(base + oSort);
        int*            cnt2   = (int*)(base + oCnt2);
        float*          posArr = (float*)(base + oPosA);

        prep_kernel<<<kPrep8Blocks, 256, 0, stream>>>(
            feats_s, f_t, idx, cidx, mem_s, mem_t, tab, sorted, cnt2, posArr, ws);
        mlcpc_l2_kernel<<<kB * 8, 256, 0, stream>>>(
            feats_s, f_t, (const int4*)tab, sorted, cnt2, ws);
        finalize2_kernel<<<1, 64, 0, stream>>>(ws, posArr, out);
    } else {
        init_ws_kernel<<<1, 64, 0, stream>>>(ws);
        mlcpc_main_kernel<<<dim3(kB, 8), 256, 0, stream>>>(feats_s, f_t, idx, cidx,
                                                           mem_s, mem_t, ws);
        finalize_kernel<<<1, 64, 0, stream>>>(ws, out);
    }
}

// Round 11
// 69.158 us; speedup vs baseline: 1.9290x; 1.5817x over previous
//
#include <hip/hip_runtime.h>
#include <cmath>

namespace {
constexpr int kB  = 256;
constexpr int kK1 = 4097;   // NCE_K + 1
constexpr int kN  = 100000; // N_DATA
constexpr float kInvT = 1.0f / 0.07f;
constexpr float kInvM = 1.0f / 4096.0f;
constexpr double kInvMd = 1.0 / 4096.0;
constexpr float kStdv = 0.15309311f;           // 1/sqrt(128/3)
constexpr float kQScale = 127.0f / kStdv;      // table quantize
constexpr float kQh    = 127.0f / 6.0f;        // query hi quant (clip +-6)
constexpr float kQhInv = 6.0f / 127.0f;
constexpr float kQl    = 127.0f * 127.0f / 6.0f;
constexpr float kDotT = (kStdv * 6.0f) / (127.0f * 127.0f * 127.0f * 0.07f);

// ---- primary (R8-structure) layout ----
constexpr int kSliceRows = 12500;   // kN / 8 XCD slices
constexpr int kCap = 704;           // per-(b,slice) bucket capacity (512 + 9 sigma)
constexpr size_t oTab  = 512;
constexpr size_t oSort = oTab + (size_t)kN * 256;            // 25,600,512
constexpr size_t oCnt2 = oSort + (size_t)kB * 8 * kCap * 2;  // 28,484,096
constexpr size_t oPosA = oCnt2 + 2048 * 4;                   // 28,492,288
constexpr size_t kNeedFull = oPosA + (size_t)kB * 5 * 4;     // 28,497,408

// prep block roles — latency-bound small blocks FIRST (overlap conv, no tail)
constexpr int kScatBase = 0;                   // [0,256): per-b scatter
constexpr int kPosBase  = kScatBase + kB;      // [256,264): positives
constexpr int kConvBase = kPosBase + 8;        // [264, 264+6250): table conv
constexpr int kConvBlocks = (kN * 16) / 256;   // 6250
constexpr int kPrepBlocks = kConvBase + kConvBlocks;   // 6514
}

__device__ __forceinline__ int sdot4i(int a, int b, int c) {
#if __has_builtin(__builtin_amdgcn_sdot4)
    return __builtin_amdgcn_sdot4(a, b, c, false);
#else
    c += (int)(signed char)(a) * (int)(signed char)(b);
    c += (int)(signed char)(a >> 8) * (int)(signed char)(b >> 8);
    c += (int)(signed char)(a >> 16) * (int)(signed char)(b >> 16);
    c += (a >> 24) * (b >> 24);
    return c;
#endif
}

__device__ __forceinline__ int q8(float v, float s) {
    int q = __float2int_rn(v * s);
    return min(127, max(-127, q));
}

__device__ __forceinline__ int pack4(int a, int b, int c, int d) {
    return (a & 255) | ((b & 255) << 8) | ((c & 255) << 16) | ((d & 255) << 24);
}

// ---------------------------- fused prep kernel ------------------------------
// [0,256): per-b LDS counting scatter; [256,264): exact-f32 positives;
// [264,6514): f32->int8 table conversion (bandwidth phase, overlaps the
// latency-bound blocks that were dispatched first).
__global__ __launch_bounds__(256) void prep_kernel(
    const float* __restrict__ feats_s, const float* __restrict__ f_t,
    const int* __restrict__ idx, const int* __restrict__ cidx,
    const float* __restrict__ mem_s, const float* __restrict__ mem_t,
    int4* __restrict__ tab, unsigned short* __restrict__ sorted,
    int* __restrict__ cnt2, float* __restrict__ posArr,
    double* __restrict__ ws)
{
    __shared__ int posc[8];
    const int blk = blockIdx.x;
    const int tid = threadIdx.x;

    if (blk >= kConvBase) {
        // ---- table conversion: one int4 (16 int8) per thread ----
        const int g = (blk - kConvBase) * 256 + tid;
        const int row  = g >> 4;
        const int r16  = g & 15;
        const int part = r16 >> 3;        // 0 = s, 1 = t
        const int u    = r16 & 7;
        const float4* src = reinterpret_cast<const float4*>(part ? mem_t : mem_s)
                            + (size_t)row * 32 + u * 4;
        int w[4];
#pragma unroll
        for (int j = 0; j < 4; ++j) {
            const float4 v = src[j];
            w[j] = pack4(q8(v.x, kQScale), q8(v.y, kQScale),
                         q8(v.z, kQScale), q8(v.w, kQScale));
        }
        tab[g] = make_int4(w[0], w[1], w[2], w[3]);
    } else if (blk < kPosBase) {
        // ---- counting scatter for b: LDS counters only ----
        const int b = blk - kScatBase;
        if (tid < 8) posc[tid] = 0;
        if (blk == kScatBase && tid < 10) ws[tid] = 0.0;
        __syncthreads();
        for (int i = tid; i < 4096; i += 256) {
            const int r = cidx[(size_t)b * kK1 + 1 + i];
            const int s = r / kSliceRows;
            const int p = atomicAdd(&posc[s], 1);   // LDS atomic
            if (p < kCap)
                sorted[(size_t)(b * 8 + s) * kCap + p] =
                    (unsigned short)(r - s * kSliceRows);
        }
        __syncthreads();
        if (tid < 8) cnt2[b * 8 + tid] = posc[tid];
    } else {
        // ---- exact-f32 positives: one octet per b, 32 octets per block ----
        const int b  = (blk - kPosBase) * 32 + (tid >> 3);
        const int ol = tid & 7;
        const int row = idx[b];
        const float4* wsr = reinterpret_cast<const float4*>(mem_s + (size_t)row * 128);
        const float4* wtr = reinterpret_cast<const float4*>(mem_t + (size_t)row * 128);
        const float4* pft = reinterpret_cast<const float4*>(f_t + (size_t)b * 128);
        float d[5] = {0.f, 0.f, 0.f, 0.f, 0.f};
#pragma unroll
        for (int j = 0; j < 4; ++j) {
            const int e = ol + 8 * j;
            const float4 a  = wsr[e];
            const float4 c  = wtr[e];
            const float4 f0 = pft[e];
            d[0] += a.x * f0.x + a.y * f0.y + a.z * f0.z + a.w * f0.w;
#pragma unroll
            for (int q = 1; q < 5; ++q) {
                const float4 g = reinterpret_cast<const float4*>(
                    feats_s + ((size_t)(q - 1) * kB + b) * 128)[e];
                d[q] += c.x * g.x + c.y * g.y + c.z * g.z + c.w * g.w;
            }
        }
#pragma unroll
        for (int off = 1; off <= 4; off <<= 1)
#pragma unroll
            for (int q = 0; q < 5; ++q) d[q] += __shfl_xor(d[q], off);
        if (ol == 0) {
#pragma unroll
            for (int q = 0; q < 5; ++q) posArr[b * 5 + q] = d[q] * kInvT;
        }
    }
}

// --------------------- slice-sorted main (XCD-L2-resident) -------------------
// block g -> (b = g>>3, slice = g&7); round-robin blockIdx->XCD puts slice s
// on XCD s, so each XCD touches only its 3.2MB table slice. Kernel sits at the
// per-CU scattered-gather cap (~0.156 lines/cy/CU, 4 lines/ref) — measured
// invariant across L2/L3 serving and MLP depth (R1/R3/R8).
__global__ __launch_bounds__(256) void mlcpc_l2_kernel(
    const float* __restrict__ feats_s,
    const float* __restrict__ f_t,
    const int4*  __restrict__ tab,
    const unsigned short* __restrict__ sorted,
    const int*   __restrict__ cnt2,
    double*      __restrict__ ws)
{
    __shared__ alignas(16) int sqh[5][32];
    __shared__ alignas(16) int sql[5][32];
    __shared__ unsigned short slst[kCap];
    __shared__ double sred[4][5];

    const int g   = blockIdx.x;
    const int s   = g & 7;
    const int b   = g >> 3;
    const int tid = threadIdx.x;

    // quantize this b's queries to hi/lo int8 words
    for (int i = tid; i < 160; i += 256) {
        const int q = i >> 5, w = i & 31;
        const float4 v = (q == 0)
            ? reinterpret_cast<const float4*>(f_t + (size_t)b * 128)[w]
            : reinterpret_cast<const float4*>(feats_s + ((size_t)(q - 1) * kB + b) * 128)[w];
        const float x[4] = {v.x, v.y, v.z, v.w};
        int h[4], l[4];
#pragma unroll
        for (int j = 0; j < 4; ++j) {
            h[j] = q8(x[j], kQh);
            l[j] = q8(x[j] - (float)h[j] * kQhInv, kQl);
        }
        sqh[q][w] = pack4(h[0], h[1], h[2], h[3]);
        sql[q][w] = pack4(l[0], l[1], l[2], l[3]);
    }
    // stage this bucket's row list into LDS
    const int len = min(cnt2[g], kCap);
    {
        const unsigned short* lst = sorted + (size_t)g * kCap;
        for (int i = tid; i < len; i += 256) slst[i] = lst[i];
    }
    __syncthreads();

    const int ol = tid & 7;
    const int oq = tid >> 3;   // 32 octets

    int qh[5][4], ql[5][4];
#pragma unroll
    for (int q = 0; q < 5; ++q) {
        const int4 th = reinterpret_cast<const int4*>(sqh[q])[ol];
        const int4 tl = reinterpret_cast<const int4*>(sql[q])[ol];
        qh[q][0] = th.x; qh[q][1] = th.y; qh[q][2] = th.z; qh[q][3] = th.w;
        ql[q][0] = tl.x; ql[q][1] = tl.y; ql[q][2] = tl.z; ql[q][3] = tl.w;
    }

    const int rowbase = s * kSliceRows;
    float aqr = 0.f;   // role accumulator (role = ol, valid ol < 5)

    // 3-deep software pipeline over this octet's refs (f = oq, oq+32, ...)
    int f = oq;
    bool v0 = f < len;
    bool v1 = (f + 32) < len;
    int4 S0, T0, S1, T1;
    if (v0) {
        const int4* rp = tab + (size_t)(rowbase + slst[f]) * 16;
        S0 = rp[ol]; T0 = rp[8 + ol];
    }
    if (v1) {
        const int4* rp = tab + (size_t)(rowbase + slst[f + 32]) * 16;
        S1 = rp[ol]; T1 = rp[8 + ol];
    }
    while (v0) {
        const bool v2 = (f + 64) < len;
        int4 S2, T2;
        if (v2) {
            const int4* rp = tab + (size_t)(rowbase + slst[f + 64]) * 16;
            S2 = rp[ol]; T2 = rp[8 + ol];
        }

        const int Sw[4] = {S0.x, S0.y, S0.z, S0.w};
        const int Tw[4] = {T0.x, T0.y, T0.z, T0.w};
        int X[5];
        {
            int h = 0, l = 0;
#pragma unroll
            for (int w = 0; w < 4; ++w) {
                h = sdot4i(Sw[w], qh[0][w], h);
                l = sdot4i(Sw[w], ql[0][w], l);
            }
            X[0] = 127 * h + l;
        }
#pragma unroll
        for (int q = 1; q < 5; ++q) {
            int h = 0, l = 0;
#pragma unroll
            for (int w = 0; w < 4; ++w) {
                h = sdot4i(Tw[w], qh[q][w], h);
                l = sdot4i(Tw[w], ql[q][w], l);
            }
            X[q] = 127 * h + l;
        }
#pragma unroll
        for (int off = 1; off <= 4; off <<= 1)
#pragma unroll
            for (int q = 0; q < 5; ++q) X[q] += __shfl_xor(X[q], off);
        if (ol < 5) aqr += expf((float)X[ol] * kDotT);

        S0 = S1; T0 = T1; S1 = S2; T1 = T2;
        v0 = v1; v1 = v2; f += 32;
    }

    // fold octets: lane L (<8) accumulates role L across the wave's 8 octets
#pragma unroll
    for (int off = 8; off <= 32; off <<= 1) aqr += __shfl_down(aqr, off);
    const int lane = tid & 63;
    const int wid  = tid >> 6;
    if (lane < 5) sred[wid][lane] = (double)aqr;
    __syncthreads();
    if (tid < 5) {
        const double v = sred[0][tid] + sred[1][tid] + sred[2][tid] + sred[3][tid];
        atomicAdd(&ws[tid], v);
    }
}

__global__ void finalize2_kernel(const double* __restrict__ ws,
                                 const float* __restrict__ posArr,
                                 float* __restrict__ out) {
    const int t = threadIdx.x;   // 64 threads
    double e[5] = {0, 0, 0, 0, 0};
    double p[5] = {0, 0, 0, 0, 0};
    for (int b = t; b < kB; b += 64) {
#pragma unroll
        for (int q = 0; q < 5; ++q) {
            const double st = (double)posArr[b * 5 + q];
            p[q] += st;
            e[q] += exp(st);
        }
    }
#pragma unroll
    for (int off = 32; off >= 1; off >>= 1)
#pragma unroll
        for (int q = 0; q < 5; ++q) {
            e[q] += __shfl_down(e[q], off);
            p[q] += __shfl_down(p[q], off);
        }
    if (t == 0) {
        const double invB = 1.0 / 256.0;
        const double loss_t = 4.0 * (-(p[0] * invB) + log((ws[0] + kInvMd * e[0]) * invB));
        double loss_s = 0.0;
#pragma unroll
        for (int n = 1; n < 5; ++n)
            loss_s += -(p[n] * invB) + log((ws[n] + kInvMd * e[n]) * invB);
        out[0] = (float)(loss_s + loss_t);
    }
}

// ------------------------- f32 fallback (round-1, known-good) ----------------
__global__ void init_ws_kernel(double* __restrict__ ws) {
    if (threadIdx.x < 10) ws[threadIdx.x] = 0.0;
}

__global__ __launch_bounds__(256) void mlcpc_main_kernel(
    const float* __restrict__ feats_s, const float* __restrict__ f_t,
    const int* __restrict__ idx, const int* __restrict__ cidx,
    const float* __restrict__ mem_s, const float* __restrict__ mem_t,
    double* __restrict__ ws)
{
    __shared__ float4 shf[5][32];
    __shared__ double sred[4][5];
    const int b = blockIdx.x, tid = threadIdx.x;
    for (int i = tid; i < 160; i += 256) {
        const int which = i >> 5, off = i & 31;
        const float* src = (which == 0) ? (f_t + (size_t)b * 128)
                                        : (feats_s + ((size_t)(which - 1) * kB + b) * 128);
        shf[which][off] = reinterpret_cast<const float4*>(src)[off];
    }
    __syncthreads();
    const int ql2 = tid & 3, gq = blockIdx.y * 64 + (tid >> 2);
    float aqt = 0.f, aq0 = 0.f, aq1 = 0.f, aq2 = 0.f, aq3 = 0.f;
    for (int k = gq; k < kK1; k += 512) {
        const int row = (k == 0) ? idx[b] : cidx[(size_t)b * kK1 + k];
        const float4* wsr = reinterpret_cast<const float4*>(mem_s + (size_t)row * 128);
        const float4* wtr = reinterpret_cast<const float4*>(mem_t + (size_t)row * 128);
        float dt = 0.f, d0 = 0.f, d1 = 0.f, d2 = 0.f, d3 = 0.f;
#pragma unroll
        for (int j = 0; j < 8; ++j) {
            const int e = ql2 + j * 4;
            const float4 a = wsr[e], c = wtr[e];
            const float4 ft = shf[0][e], g0 = shf[1][e], g1 = shf[2][e],
                         g2 = shf[3][e], g3 = shf[4][e];
            dt += a.x * ft.x + a.y * ft.y + a.z * ft.z + a.w * ft.w;
            d0 += c.x * g0.x + c.y * g0.y + c.z * g0.z + c.w * g0.w;
            d1 += c.x * g1.x + c.y * g1.y + c.z * g1.z + c.w * g1.w;
            d2 += c.x * g2.x + c.y * g2.y + c.z * g2.z + c.w * g2.w;
            d3 += c.x * g3.x + c.y * g3.y + c.z * g3.z + c.w * g3.w;
        }
#pragma unroll
        for (int off = 1; off <= 2; off <<= 1) {
            dt += __shfl_xor(dt, off); d0 += __shfl_xor(d0, off);
            d1 += __shfl_xor(d1, off); d2 += __shfl_xor(d2, off);
            d3 += __shfl_xor(d3, off);
        }
        if (ql2 == 0) {
            const float st = dt * kInvT, s0 = d0 * kInvT, s1 = d1 * kInvT,
                        s2 = d2 * kInvT, s3 = d3 * kInvT;
            const float w = (k == 0) ? kInvM : 1.0f;
            aqt += w * expf(st); aq0 += w * expf(s0); aq1 += w * expf(s1);
            aq2 += w * expf(s2); aq3 += w * expf(s3);
            if (k == 0) {
                atomicAdd(&ws[5], (double)st); atomicAdd(&ws[6], (double)s0);
                atomicAdd(&ws[7], (double)s1); atomicAdd(&ws[8], (double)s2);
                atomicAdd(&ws[9], (double)s3);
            }
        }
    }
#pragma unroll
    for (int off = 32; off >= 1; off >>= 1) {
        aqt += __shfl_down(aqt, off); aq0 += __shfl_down(aq0, off);
        aq1 += __shfl_down(aq1, off); aq2 += __shfl_down(aq2, off);
        aq3 += __shfl_down(aq3, off);
    }
    const int lane = tid & 63, wid = tid >> 6;
    if (lane == 0) {
        sred[wid][0] = (double)aqt; sred[wid][1] = (double)aq0;
        sred[wid][2] = (double)aq1; sred[wid][3] = (double)aq2;
        sred[wid][4] = (double)aq3;
    }
    __syncthreads();
    if (tid < 5) {
        const double sv = sred[0][tid] + sred[1][tid] + sred[2][tid] + sred[3][tid];
        atomicAdd(&ws[tid], sv);
    }
}

__global__ void finalize_kernel(const double* __restrict__ ws, float* __restrict__ out) {
    if (threadIdx.x == 0 && blockIdx.x == 0) {
        const double invB = 1.0 / 256.0;
        double loss_t = 4.0 * (-(ws[5] * invB) + log(ws[0] * invB));
        double loss_s = 0.0;
        for (int n = 0; n < 4; ++n)
            loss_s += -(ws[6 + n] * invB) + log(ws[1 + n] * invB);
        out[0] = (float)(loss_s + loss_t);
    }
}

// ----------------------------------- launch ----------------------------------
extern "C" void kernel_launch(void* const* d_in, const int* in_sizes, int n_in,
                              void* d_out, int out_size, void* d_ws, size_t ws_size,
                              hipStream_t stream) {
    const float* feats_s = (const float*)d_in[0];
    const float* f_t     = (const float*)d_in[1];
    const int*   idx     = (const int*)d_in[2];
    const int*   cidx    = (const int*)d_in[3];
    const float* mem_s   = (const float*)d_in[4];
    const float* mem_t   = (const float*)d_in[5];
    float* out = (float*)d_out;
    double* ws = (double*)d_ws;
    char* base = (char*)d_ws;

    if (ws_size >= kNeedFull) {
        int4*           tab    = (int4*)(base + oTab);
        unsigned short* sorted = (unsigned short*)(base + oSort);
        int*            cnt2   = (int*)(base + oCnt2);
        float*          posArr = (float*)(base + oPosA);

        prep_kernel<<<kPrepBlocks, 256, 0, stream>>>(
            feats_s, f_t, idx, cidx, mem_s, mem_t, tab, sorted, cnt2, posArr, ws);
        mlcpc_l2_kernel<<<kB * 8, 256, 0, stream>>>(
            feats_s, f_t, (const int4*)tab, sorted, cnt2, ws);
        finalize2_kernel<<<1, 64, 0, stream>>>(ws, posArr, out);
    } else {
        init_ws_kernel<<<1, 64, 0, stream>>>(ws);
        mlcpc_main_kernel<<<dim3(kB, 8), 256, 0, stream>>>(feats_s, f_t, idx, cidx,
                                                           mem_s, mem_t, ws);
        finalize_kernel<<<1, 64, 0, stream>>>(ws, out);
    }
}